// Round 20
// baseline (324.357 us; speedup 1.0000x reference)
//
#include <hip/hip_runtime.h>
#include <hip/hip_bf16.h>
#include <cstdint>

// Problem constants
#define PB 4
#define PS 2048
#define PE 1024
#define PH 16
#define PD 64
#define PM (PB * PS)      // 8192 rows

typedef __attribute__((ext_vector_type(8))) _Float16 half8;  // 8 fp16 (4 VGPR)
typedef __attribute__((ext_vector_type(4))) float f32x4;

#define MFMAH __builtin_amdgcn_mfma_f32_16x16x32_f16

#define GLOAD_LDS(gp, lp) __builtin_amdgcn_global_load_lds(                    \
    (const __attribute__((address_space(1))) void*)(gp),                       \
    (__attribute__((address_space(3))) void*)(lp), 16, 0, 0)

#if __has_builtin(__builtin_amdgcn_exp2f)
#define FAST_EXP2 1
#define QSC (0.125f * 1.4426950408889634f)   // exp2 domain
#define FTHR 11.5415603f                     // 8*log2(e)
#define EXP_P(x) __builtin_amdgcn_exp2f(x)
#else
#define FAST_EXP2 0
#define QSC 0.125f
#define FTHR 8.f
#define EXP_P(x) __expf(x)
#endif

// fp32 -> fp16 RNE bit pattern
__device__ inline unsigned short h16(float x) {
    _Float16 h = (_Float16)x;
    unsigned short u;
    __builtin_memcpy(&u, &h, 2);
    return u;
}
__device__ inline float f16tof(unsigned short u) {
    _Float16 h;
    __builtin_memcpy(&h, &u, 2);
    return (float)h;
}
// packed fp16 pair via v_cvt_pkrtz_f16_f32; returns the 32-bit word
__device__ inline unsigned pkrtz(float a, float b) {
    auto p = __builtin_amdgcn_cvt_pkrtz(a, b);   // __fp16 ext_vector(2)
    unsigned u;
    __builtin_memcpy(&u, &p, 4);
    return u;
}
// RNE variant used where split_all previously produced RNE values
__device__ inline unsigned pk2rn(float a, float b) {
    unsigned u = (unsigned)h16(a) | ((unsigned)h16(b) << 16);
    return u;
}

// ---------------------------------------------------------------------------
// split_w: the 6 weight matrices -> fp16 planes (query handled inline now).
// f4 ranges: Wq/Wk/Wv/Wo 262144 each | Wm1/Wm2 65536 each. grid 4608.
// ---------------------------------------------------------------------------
__global__ __launch_bounds__(256)
void split_w(const float* __restrict__ wq,  const float* __restrict__ wk,
             const float* __restrict__ wv,  const float* __restrict__ wo,
             const float* __restrict__ wm1, const float* __restrict__ wm2,
             unsigned short* wqh, unsigned short* wkh,
             unsigned short* wvh, unsigned short* woh,
             unsigned short* m1h, unsigned short* m2h)
{
    const int b = blockIdx.x;
    const float* src; unsigned short* dst; int base;
    if      (b < 1024) { src = wq;  dst = wqh; base = 0;    }
    else if (b < 2048) { src = wk;  dst = wkh; base = 1024; }
    else if (b < 3072) { src = wv;  dst = wvh; base = 2048; }
    else if (b < 4096) { src = wo;  dst = woh; base = 3072; }
    else if (b < 4352) { src = wm1; dst = m1h; base = 4096; }
    else               { src = wm2; dst = m2h; base = 4352; }
    const int i = (b - base) * 256 + threadIdx.x;
    float4 f = ((const float4*)src)[i];
    ushort4 h;
    h.x = h16(f.x); h.y = h16(f.y); h.z = h16(f.z); h.w = h16(f.w);
    ((ushort4*)dst)[i] = h;
}

// ---------------------------------------------------------------------------
// Fused QKV projection v3: A read directly from fp32 query, converted
// in-flight (T14 split: issue next-step A loads before compute, convert +
// ds_write after compute into the idle buffer). W planes via global_load_lds
// (6 x 1KB chunks per wave across 8 waves). 512 threads, 128KB dbuf LDS.
// Epilogues unchanged: Q fp16 pre-scaled BHSD, K fp16 BHSD, V fp16 BHDS
// with PV seq permutation.
// ---------------------------------------------------------------------------
__global__ __launch_bounds__(512, 1)
void gemm_qkv(const float* __restrict__ Aq,
              const unsigned short* __restrict__ Wqh,
              const unsigned short* __restrict__ Wkh,
              const unsigned short* __restrict__ Wvh,
              const float* __restrict__ bq, const float* __restrict__ bk,
              const float* __restrict__ bv,
              unsigned short* __restrict__ qh16, unsigned short* __restrict__ kf,
              unsigned short* __restrict__ vtf)
{
    __shared__ int4 ldsq[8192];                 // 128 KB = 2 bufs x 4 planes
    char* const lds = (char*)ldsq;
    const int K = PE;

    const int tid  = threadIdx.x;
    const int lane = tid & 63;
    const int w    = tid >> 6;
    const int lq   = lane & 15;
    const int lg   = lane >> 4;
    const int wr   = w >> 2;
    const int wc   = w & 3;
    const int m0   = blockIdx.x * 128;
    const int n0   = blockIdx.y * 128;

    const int scol8 = (((lane & 7) ^ (lane >> 3)) << 3);
    const int lrow8 = lane >> 3;

    // A conversion: thread owns granules 2*tid, 2*tid+1 of the 128x128B tile
    const int arow = tid >> 2;                  // 0..127
    const int agc0 = (2 * tid) & 7;             // granule col (even)
    const int aswz = (arow & 7) << 4;
    const float* const asrc0 = Aq + (size_t)(m0 + arow) * K + agc0 * 8;
    const int ad0 = arow * 128 + ((agc0 * 16) ^ aswz);
    const int ad1 = arow * 128 + (((agc0 + 1) * 16) ^ aswz);

    auto LOADA = [&](int k0, float4* a) {
        const float4* p = (const float4*)(asrc0 + k0);
        a[0] = p[0]; a[1] = p[1]; a[2] = p[2]; a[3] = p[3];
    };
    auto CVTW = [&](const float4* a, int bufn) {
        uint4 g0 = make_uint4(pk2rn(a[0].x, a[0].y), pk2rn(a[0].z, a[0].w),
                              pk2rn(a[1].x, a[1].y), pk2rn(a[1].z, a[1].w));
        uint4 g1 = make_uint4(pk2rn(a[2].x, a[2].y), pk2rn(a[2].z, a[2].w),
                              pk2rn(a[3].x, a[3].y), pk2rn(a[3].z, a[3].w));
        *(uint4*)(lds + bufn * 65536 + ad0) = g0;
        *(uint4*)(lds + bufn * 65536 + ad1) = g1;
    };
    auto WISSUE = [&](int k0, int bufn) {
        #pragma unroll
        for (int r = 0; r < 6; ++r) {
            const int c = w * 6 + r;            // 0..47
            const int p = c >> 4;               // 0..2
            const int lc = c & 15;
            const unsigned short* wp = (p == 0) ? Wqh : (p == 1) ? Wkh : Wvh;
            GLOAD_LDS(wp + (size_t)(n0 + lc * 8 + lrow8) * K + k0 + scol8,
                      lds + bufn * 65536 + (p + 1) * 16384 + lc * 1024 + 16 * lane);
        }
    };

    f32x4 acc[3][4][2];
    #pragma unroll
    for (int o = 0; o < 3; ++o)
        #pragma unroll
        for (int mt = 0; mt < 4; ++mt)
            #pragma unroll
            for (int nt = 0; nt < 2; ++nt)
                acc[o][mt][nt] = (f32x4){0.f, 0.f, 0.f, 0.f};

    {
        float4 a0[4];
        LOADA(0, a0);
        WISSUE(0, 0);
        CVTW(a0, 0);
    }
    __syncthreads();

    int buf = 0;
    for (int k0 = 0; k0 < K; k0 += 64) {
        const bool more = (k0 + 64 < K);
        float4 an[4];
        if (more) {
            LOADA(k0 + 64, an);
            WISSUE(k0 + 64, buf ^ 1);
        }

        const char* const L = lds + buf * 65536;
        #pragma unroll
        for (int kh = 0; kh < 2; ++kh) {
            half8 af[4];
            #pragma unroll
            for (int mt = 0; mt < 4; ++mt) {
                const int row = 64 * wr + 16 * mt + lq;
                const int off = row * 128 + ((kh * 64 + 16 * lg) ^ ((row & 7) << 4));
                af[mt] = *(const half8*)(L + off);
            }
            #pragma unroll
            for (int o = 0; o < 3; ++o) {
                #pragma unroll
                for (int nt = 0; nt < 2; ++nt) {
                    const int row = 32 * wc + 16 * nt + lq;
                    const int off = row * 128 + ((kh * 64 + 16 * lg) ^ ((row & 7) << 4));
                    half8 bf = *(const half8*)(L + 16384 * (o + 1) + off);
                    #pragma unroll
                    for (int mt = 0; mt < 4; ++mt)
                        acc[o][mt][nt] = MFMAH(af[mt], bf, acc[o][mt][nt], 0, 0, 0);
                }
            }
        }
        if (more) CVTW(an, buf ^ 1);
        __syncthreads();
        buf ^= 1;
    }

    #pragma unroll
    for (int nt = 0; nt < 2; ++nt) {
        const int n = n0 + 32 * wc + 16 * nt + lq;
        const int h = n >> 6, d = n & 63;
        const float bqv = bq[n], bkv = bk[n], bvv = bv[n];
        #pragma unroll
        for (int mt = 0; mt < 4; ++mt) {
            #pragma unroll
            for (int j = 0; j < 4; ++j) {
                const int m = m0 + 64 * wr + 16 * mt + 4 * lg + j;
                const int b = m >> 11, s = m & 2047;
                qh16[((size_t)(b * PH + h) * PS + s) * PD + d] =
                    h16((acc[0][mt][nt][j] + bqv) * QSC);
                kf[((size_t)(b * PH + h) * PS + s) * PD + d] =
                    h16(acc[1][mt][nt][j] + bkv);
                const int scol = (s & ~63) + ((mt & 1) << 5) + (lg << 3)
                               + ((mt >> 1) << 2) + j;
                vtf[((size_t)(b * PH + h) * PD + d) * PS + scol] =
                    h16(acc[2][mt][nt][j] + bvv);
            }
        }
    }
}

// ---------------------------------------------------------------------------
// MLP layer 1: A fp32 query converted in-flight (4 granules/thread, T14),
// B = Wm1 fp16 plane via global_load_lds. 256 threads, 64KB dbuf LDS.
// Output: h1 fp16 plane [M][256] with RELU.
// ---------------------------------------------------------------------------
__global__ __launch_bounds__(256, 1)
void gemm_m1(const float* __restrict__ Aq,
             const unsigned short* __restrict__ Bh,
             const float* __restrict__ bias,
             unsigned short* __restrict__ Oh)
{
    __shared__ int4 ldsq[4096];                 // 64 KB = 2 bufs x 32 KB
    char* const lds = (char*)ldsq;
    const int K = PE, N = 256;

    const int tid  = threadIdx.x;
    const int lane = tid & 63;
    const int w    = tid >> 6;
    const int lq   = lane & 15;
    const int lg   = lane >> 4;
    const int wm   = (w >> 1) * 64;
    const int wn   = (w & 1) * 64;
    const int m0   = blockIdx.x * 128;
    const int n0   = blockIdx.y * 128;

    const int scol8 = (((lane & 7) ^ (lane >> 3)) << 3);
    const int lrow8 = lane >> 3;

    // A conversion: thread owns granules 4*tid..4*tid+3
    const int arow = tid >> 1;                  // 0..127
    const int agc0 = (tid & 1) * 4;             // 0 or 4
    const int aswz = (arow & 7) << 4;
    const float* const asrc0 = Aq + (size_t)(m0 + arow) * K + agc0 * 8;

    auto LOADA = [&](int k0, float4* a) {
        const float4* p = (const float4*)(asrc0 + k0);
        #pragma unroll
        for (int i = 0; i < 8; ++i) a[i] = p[i];
    };
    auto CVTW = [&](const float4* a, int bufn) {
        #pragma unroll
        for (int g = 0; g < 4; ++g) {
            uint4 gv = make_uint4(pk2rn(a[2*g].x, a[2*g].y),
                                  pk2rn(a[2*g].z, a[2*g].w),
                                  pk2rn(a[2*g+1].x, a[2*g+1].y),
                                  pk2rn(a[2*g+1].z, a[2*g+1].w));
            const int off = arow * 128 + (((agc0 + g) * 16) ^ aswz);
            *(uint4*)(lds + bufn * 32768 + off) = gv;
        }
    };
    auto WISSUE = [&](int k0, int bufn) {
        #pragma unroll
        for (int r = 0; r < 4; ++r) {
            const int c = w * 4 + r;            // 0..15
            GLOAD_LDS(Bh + (size_t)(n0 + c * 8 + lrow8) * K + k0 + scol8,
                      lds + bufn * 32768 + 16384 + c * 1024 + 16 * lane);
        }
    };

    f32x4 acc[4][4];
    #pragma unroll
    for (int mt = 0; mt < 4; ++mt)
        #pragma unroll
        for (int nt = 0; nt < 4; ++nt)
            acc[mt][nt] = (f32x4){0.f, 0.f, 0.f, 0.f};

    {
        float4 a0[8];
        LOADA(0, a0);
        WISSUE(0, 0);
        CVTW(a0, 0);
    }
    __syncthreads();

    int buf = 0;
    for (int k0 = 0; k0 < K; k0 += 64) {
        const bool more = (k0 + 64 < K);
        float4 an[8];
        if (more) {
            LOADA(k0 + 64, an);
            WISSUE(k0 + 64, buf ^ 1);
        }

        const char* const L = lds + buf * 32768;
        #pragma unroll
        for (int kh = 0; kh < 2; ++kh) {
            half8 af[4];
            #pragma unroll
            for (int mt = 0; mt < 4; ++mt) {
                const int row = wm + 16 * mt + lq;
                const int off = row * 128 + ((kh * 64 + 16 * lg) ^ ((row & 7) << 4));
                af[mt] = *(const half8*)(L + off);
            }
            #pragma unroll
            for (int nt = 0; nt < 4; ++nt) {
                const int row = wn + 16 * nt + lq;
                const int off = row * 128 + ((kh * 64 + 16 * lg) ^ ((row & 7) << 4));
                half8 bf = *(const half8*)(L + 16384 + off);
                #pragma unroll
                for (int mt = 0; mt < 4; ++mt)
                    acc[mt][nt] = MFMAH(af[mt], bf, acc[mt][nt], 0, 0, 0);
            }
        }
        if (more) CVTW(an, buf ^ 1);
        __syncthreads();
        buf ^= 1;
    }

    #pragma unroll
    for (int nt = 0; nt < 4; ++nt) {
        const int n  = n0 + wn + 16 * nt + lq;
        const float bv = bias[n];
        #pragma unroll
        for (int mt = 0; mt < 4; ++mt) {
            #pragma unroll
            for (int j = 0; j < 4; ++j) {
                const int m = m0 + wm + 16 * mt + 4 * lg + j;
                float v = fmaxf(acc[mt][nt][j] + bv, 0.f);
                Oh[(size_t)m * N + n] = h16(v);
            }
        }
    }
}

// ---------------------------------------------------------------------------
// Plane-fed single-fp16 MFMA NT GEMM (round-15 proven engine, unchanged).
// MODE 0: fp32 C[m*N+n] (optional RELU) | MODE 5: fp16 plane [M][N]
// ---------------------------------------------------------------------------
template<int MODE, bool RELU>
__global__ __launch_bounds__(256, 2)
void gemm_pl(const unsigned short* __restrict__ Ah,
             const unsigned short* __restrict__ Bh,
             const float* __restrict__ bias, float* __restrict__ C,
             unsigned short* __restrict__ Oh,
             int M, int N, int K)
{
    __shared__ int4 ldsq[4096];                 // 64 KB = 2 bufs x 32 KB
    char* const lds = (char*)ldsq;

    const int tid  = threadIdx.x;
    const int lane = tid & 63;
    const int w    = tid >> 6;
    const int lq   = lane & 15;
    const int lg   = lane >> 4;
    const int wm   = (w >> 1) * 64;
    const int wn   = (w & 1) * 64;
    const int m0   = blockIdx.x * 128;
    const int n0   = blockIdx.y * 128;

    const unsigned short* const gp =
        (w < 2) ? Ah + (size_t)m0 * K : Bh + (size_t)n0 * K;
    const int pb    = (w < 2) ? 0 : 16384;
    const int ch0   = (w & 1) * 8;
    const int scol8 = (((lane & 7) ^ (lane >> 3)) << 3);
    const int lrow8 = lane >> 3;

    auto ISSUE = [&](int k0, int bufn) {
        #pragma unroll
        for (int r = 0; r < 8; ++r) {
            const int c   = ch0 + r;
            const int row = c * 8 + lrow8;
            GLOAD_LDS(gp + (size_t)row * K + k0 + scol8,
                      lds + bufn * 32768 + pb + c * 1024 + 16 * lane);
        }
    };

    f32x4 acc[4][4];
    #pragma unroll
    for (int mt = 0; mt < 4; ++mt)
        #pragma unroll
        for (int nt = 0; nt < 4; ++nt)
            acc[mt][nt] = (f32x4){0.f, 0.f, 0.f, 0.f};

    ISSUE(0, 0);
    __syncthreads();

    int buf = 0;
    for (int k0 = 0; k0 < K; k0 += 64) {
        if (k0 + 64 < K) ISSUE(k0 + 64, buf ^ 1);

        const char* const L = lds + buf * 32768;
        #pragma unroll
        for (int kh = 0; kh < 2; ++kh) {
            half8 af[4];
            #pragma unroll
            for (int mt = 0; mt < 4; ++mt) {
                const int row = wm + 16 * mt + lq;
                const int off = row * 128 + ((kh * 64 + 16 * lg) ^ ((row & 7) << 4));
                af[mt] = *(const half8*)(L + off);
            }
            #pragma unroll
            for (int nt = 0; nt < 4; ++nt) {
                const int row = wn + 16 * nt + lq;
                const int off = row * 128 + ((kh * 64 + 16 * lg) ^ ((row & 7) << 4));
                half8 bf = *(const half8*)(L + 16384 + off);
                #pragma unroll
                for (int mt = 0; mt < 4; ++mt)
                    acc[mt][nt] = MFMAH(af[mt], bf, acc[mt][nt], 0, 0, 0);
            }
        }
        __syncthreads();
        buf ^= 1;
    }

    #pragma unroll
    for (int nt = 0; nt < 4; ++nt) {
        const int n  = n0 + wn + 16 * nt + lq;
        const float bv = bias[n];
        #pragma unroll
        for (int mt = 0; mt < 4; ++mt) {
            #pragma unroll
            for (int j = 0; j < 4; ++j) {
                const int m = m0 + wm + 16 * mt + 4 * lg + j;
                float v = acc[mt][nt][j] + bv;
                if (RELU) v = fmaxf(v, 0.f);
                if (MODE == 0) {
                    C[(size_t)m * N + n] = v;
                } else { // MODE 5
                    Oh[(size_t)m * N + n] = h16(v);
                }
            }
        }
    }
}

// ---------------------------------------------------------------------------
// fp32-fed fallback GEMM (bf16 3-term internally, round-5 proven skeleton);
// MODE 1 emits PRE-SCALED fp16 Q; MODE 3/4 emit fp16 planes.
// ---------------------------------------------------------------------------
typedef __attribute__((ext_vector_type(8))) short short8;
#define MFMA16 __builtin_amdgcn_mfma_f32_16x16x32_bf16
__device__ inline unsigned short bf16rn(float x) {
    unsigned u = __builtin_bit_cast(unsigned, x);
    u += 0x7FFFu + ((u >> 16) & 1u);
    return (unsigned short)(u >> 16);
}
__device__ inline float bf16tof(unsigned short h) {
    unsigned u = ((unsigned)h) << 16;
    return __builtin_bit_cast(float, u);
}
__device__ inline void split2(float x, unsigned short& h, unsigned short& l) {
    h = bf16rn(x);
    l = bf16rn(x - bf16tof(h));
}

template<int MODE, bool RELU>
__global__ __launch_bounds__(256, 2)
void gemm_nt(const float* __restrict__ A, const float* __restrict__ Bw,
             const float* __restrict__ bias, float* __restrict__ C,
             unsigned short* __restrict__ Ohi,
             int M, int N, int K,
             const float* __restrict__ attn,
             const float* __restrict__ g0, const float* __restrict__ g1,
             const float* __restrict__ g2, const float* __restrict__ g3,
             const float* __restrict__ asc, const float* __restrict__ abi)
{
    __shared__ int4 ldsq[4096];
    char* const lds = (char*)ldsq;

    const int tid  = threadIdx.x;
    const int lane = tid & 63;
    const int w    = tid >> 6;
    const int lq   = lane & 15;
    const int lg   = lane >> 4;
    const int wm   = (w >> 1) * 64;
    const int wn   = (w & 1) * 64;
    const int m0   = blockIdx.x * 128;
    const int n0   = blockIdx.y * 128;

    const int irow = tid >> 3;
    const int ic8  = (tid & 7) * 8;
    const int woff = (ic8 * 2);

    f32x4 acc[4][4];
    #pragma unroll
    for (int mt = 0; mt < 4; ++mt)
        #pragma unroll
        for (int nt = 0; nt < 4; ++nt)
            acc[mt][nt] = (f32x4){0.f, 0.f, 0.f, 0.f};

    for (int k0 = 0; k0 < K; k0 += 64) {
        #pragma unroll
        for (int mat = 0; mat < 2; ++mat) {
            const float* const src = mat ? Bw : A;
            const int rbase = mat ? n0 : m0;
            const int pbase = mat ? 32768 : 0;
            #pragma unroll
            for (int r = 0; r < 4; ++r) {
                const int row = irow + 32 * r;
                const float* p = src + (size_t)(rbase + row) * K + k0 + ic8;
                float4 f0 = *(const float4*)p;
                float4 f1 = *(const float4*)(p + 4);
                short8 vh, vl;
                {
                    unsigned short h, l;
                    split2(f0.x, h, l); vh[0] = (short)h; vl[0] = (short)l;
                    split2(f0.y, h, l); vh[1] = (short)h; vl[1] = (short)l;
                    split2(f0.z, h, l); vh[2] = (short)h; vl[2] = (short)l;
                    split2(f0.w, h, l); vh[3] = (short)h; vl[3] = (short)l;
                    split2(f1.x, h, l); vh[4] = (short)h; vl[4] = (short)l;
                    split2(f1.y, h, l); vh[5] = (short)h; vl[5] = (short)l;
                    split2(f1.z, h, l); vh[6] = (short)h; vl[6] = (short)l;
                    split2(f1.w, h, l); vh[7] = (short)h; vl[7] = (short)l;
                }
                const int off = row * 128 + (woff ^ ((row & 7) << 4));
                *(short8*)(lds + pbase + off)         = vh;
                *(short8*)(lds + pbase + 16384 + off) = vl;
            }
        }
        __syncthreads();

        #pragma unroll
        for (int kh = 0; kh < 2; ++kh) {
            short8 afh[4], afl[4];
            #pragma unroll
            for (int mt = 0; mt < 4; ++mt) {
                const int row = wm + 16 * mt + lq;
                const int off = row * 128 + ((kh * 64 + 16 * lg) ^ ((row & 7) << 4));
                afh[mt] = *(const short8*)(lds + off);
                afl[mt] = *(const short8*)(lds + 16384 + off);
            }
            #pragma unroll
            for (int nt = 0; nt < 4; ++nt) {
                const int row = wn + 16 * nt + lq;
                const int off = row * 128 + ((kh * 64 + 16 * lg) ^ ((row & 7) << 4));
                short8 bfh = *(const short8*)(lds + 32768 + off);
                short8 bfl = *(const short8*)(lds + 49152 + off);
                #pragma unroll
                for (int mt = 0; mt < 4; ++mt) {
                    acc[mt][nt] = MFMA16(afh[mt], bfh, acc[mt][nt], 0, 0, 0);
                    acc[mt][nt] = MFMA16(afh[mt], bfl, acc[mt][nt], 0, 0, 0);
                    acc[mt][nt] = MFMA16(afl[mt], bfh, acc[mt][nt], 0, 0, 0);
                }
            }
        }
        __syncthreads();
    }

    float gain = 0.f, ascv = 0.f, abiv = 0.f;
    if (MODE == 2) {
        gain = 0.25f * (*g0 + *g1 + *g2 + *g3);
        ascv = *asc;
        abiv = *abi;
    }

    #pragma unroll
    for (int nt = 0; nt < 4; ++nt) {
        const int n  = n0 + wn + 16 * nt + lq;
        const float bv = bias[n];
        #pragma unroll
        for (int mt = 0; mt < 4; ++mt) {
            #pragma unroll
            for (int j = 0; j < 4; ++j) {
                const int m = m0 + wm + 16 * mt + 4 * lg + j;
                float v = acc[mt][nt][j] + bv;
                if (RELU) v = fmaxf(v, 0.f);
                if (MODE == 0) {
                    C[(size_t)m * N + n] = v;
                } else if (MODE == 1) {
                    const int b = m >> 11, s = m & 2047;
                    const int h = n >> 6, d = n & 63;
                    Ohi[((size_t)(b * PH + h) * PS + s) * PD + d] = h16(v * QSC);
                } else if (MODE == 3) {
                    const int b = m >> 11, s = m & 2047;
                    const int h = n >> 6, d = n & 63;
                    Ohi[((size_t)(b * PH + h) * PS + s) * PD + d] = h16(v);
                } else if (MODE == 4) {
                    const int b = m >> 11;
                    const int h = n >> 6, d = n & 63;
                    const int scol = (m & 2047 & ~63) + ((mt & 1) << 5)
                                   + (lg << 3) + ((mt >> 1) << 2) + j;
                    Ohi[((size_t)(b * PH + h) * PD + d) * PS + scol] = h16(v);
                } else { // MODE 2
                    const int b = m >> 11, s = m & 2047;
                    const int h = n >> 6, d = n & 63;
                    const float av = attn[((size_t)(b * PH + h) * PS + s) * PD + d];
                    C[(size_t)m * N + n] = (av * ascv + abiv) * (1.f + v * gain);
                }
            }
        }
    }
}

// ---------------------------------------------------------------------------
// MFMA flash attention v12 (round-19 proven, unchanged): biased C-init
// (st = S - m from the matrix pipe), local-max defer check, setprio around
// MFMA clusters, Q/K/V single fp16, P fp16, l via MFMA(ones,P).
// FUSE=1: epilogue applies neuromod combine -> fp16 attnf plane.
// FUSE=0: fp32 attn BHSD (fallback path).
// ---------------------------------------------------------------------------
template<int FUSE>
__global__ __launch_bounds__(256, 4)
void flash_mfma(const unsigned short* __restrict__ qh16,
                const unsigned short* __restrict__ kf,
                const unsigned short* __restrict__ vtf,
                const unsigned short* __restrict__ modh,
                const float* __restrict__ g0, const float* __restrict__ g1,
                const float* __restrict__ g2, const float* __restrict__ g3,
                const float* __restrict__ asc, const float* __restrict__ abi,
                unsigned short* __restrict__ afh, float* __restrict__ attn)
{
    __shared__ int4 ldsv[2048];                    // 32 KB: 2 bufs x (K8K + V8K)
    char* const ldsb = (char*)ldsv;

    const int tid  = threadIdx.x;
    const int lane = tid & 63;
    const int w    = tid >> 6;
    const int lq   = lane & 15;
    const int lg   = lane >> 4;

    // XCD swizzle: each XCD owns 128 consecutive logical blocks (= 8 bh).
    const int L  = blockIdx.x + (blockIdx.y << 4) + (blockIdx.z << 8);
    const int nL = ((L & 7) << 7) + (L >> 3);
    const int bh = nL >> 4;
    const int q0 = (nL & 15) * 128 + w * 32;

    const size_t kbase = (size_t)bh * PS * PD;   // K rows   [S][D]
    const size_t vbase = (size_t)bh * PD * PS;   // V^T rows [D][S] (permuted)

    const unsigned short* const gp = (w < 2) ? kf + kbase : vtf + vbase;
    const bool isK = (w < 2);
    const int ch0   = (w & 1) * 4;
    const int scol8 = (((lane & 7) ^ (lane >> 3)) << 3);   // pre-swizzled col
    const int lrow8 = lane >> 3;

    auto ISSUE = [&](int kt, int bufn) {
        #pragma unroll
        for (int r = 0; r < 4; ++r) {
            const int c   = ch0 + r;
            const int row = c * 8 + lrow8;
            const size_t goff = isK ? (size_t)(kt + row) * PD + scol8
                                    : (size_t)row * PS + kt + scol8;
            GLOAD_LDS(gp + goff,
                      ldsb + bufn * 16384 + (isK ? 0 : 8192) + c * 1024 + 16 * lane);
        }
    };

    const half8 onesh = {(_Float16)1.f, (_Float16)1.f, (_Float16)1.f,
                         (_Float16)1.f, (_Float16)1.f, (_Float16)1.f,
                         (_Float16)1.f, (_Float16)1.f};

    // ---- Q fragments: pre-scaled fp16 plane, direct vector loads
    half8 qh[2][2];
    #pragma unroll
    for (int u = 0; u < 2; ++u) {
        const unsigned short* qp =
            qh16 + ((size_t)bh * PS + q0 + 16 * u + lq) * PD + 8 * lg;
        qh[u][0] = *(const half8*)(qp);
        qh[u][1] = *(const half8*)(qp + 32);
    }

    f32x4 ot[2][4];
    #pragma unroll
    for (int u = 0; u < 2; ++u)
        #pragma unroll
        for (int mt = 0; mt < 4; ++mt)
            ot[u][mt] = (f32x4){0.f, 0.f, 0.f, 0.f};
    f32x4 lacc[2] = {{0.f,0.f,0.f,0.f}, {0.f,0.f,0.f,0.f}};
    float m_run[2] = {0.f, 0.f};           // absolute running max (biased init)

    ISSUE(0, 0);
    __syncthreads();

    int buf = 0;
    for (int kti = 0; kti < PS / 64; ++kti) {
        const bool pf = (kti + 1 < PS / 64);
        if (pf) ISSUE((kti + 1) * 64, buf ^ 1);

        const char* const L2 = ldsb + buf * 16384;

        // ---- S^T tiles with biased C-init: st = S - m_run (no subs later)
        f32x4 st[2][4];
        __builtin_amdgcn_s_setprio(1);
        #pragma unroll
        for (int mt = 0; mt < 4; ++mt) {
            const int row = 16 * mt + lq;
            const int swz = (row & 7) << 4;
            const char* kr = L2 + row * 128;
            half8 a0 = *(const half8*)(kr + ((16 * lg) ^ swz));
            half8 a1 = *(const half8*)(kr + ((64 + 16 * lg) ^ swz));
            #pragma unroll
            for (int u = 0; u < 2; ++u) {
                const float nm = -m_run[u];
                f32x4 acc = {nm, nm, nm, nm};
                acc = MFMAH(a0, qh[u][0], acc, 0, 0, 0);
                acc = MFMAH(a1, qh[u][1], acc, 0, 0, 0);
                st[u][mt] = acc;
            }
        }
        __builtin_amdgcn_s_setprio(0);

        // ---- online softmax (defer-max, biased) + P pack + l via MFMA
        half8 pb[2][2];
        #pragma unroll
        for (int u = 0; u < 2; ++u) {
            float a0 = fmaxf(fmaxf(st[u][0][0], st[u][0][1]), st[u][0][2]);
            float a1 = fmaxf(fmaxf(st[u][0][3], st[u][1][0]), st[u][1][1]);
            float a2 = fmaxf(fmaxf(st[u][1][2], st[u][1][3]), st[u][2][0]);
            float a3 = fmaxf(fmaxf(st[u][2][1], st[u][2][2]), st[u][2][3]);
            float a4 = fmaxf(fmaxf(st[u][3][0], st[u][3][1]), st[u][3][2]);
            float b0 = fmaxf(fmaxf(a0, a1), a2);
            float b1 = fmaxf(fmaxf(a3, a4), st[u][3][3]);
            float lmax = fmaxf(b0, b1);
            if (!__all(lmax <= FTHR)) {            // rare: rescale path
                float pmax = fmaxf(lmax, __shfl_xor(lmax, 16));
                pmax = fmaxf(pmax, __shfl_xor(pmax, 32));
                float corr = EXP_P(-pmax);
                m_run[u] += pmax;
                #pragma unroll
                for (int j = 0; j < 4; ++j)
                    lacc[u][j] *= corr;
                #pragma unroll
                for (int mt = 0; mt < 4; ++mt)
                    #pragma unroll
                    for (int j = 0; j < 4; ++j) {
                        ot[u][mt][j] *= corr;
                        st[u][mt][j] -= pmax;
                    }
            }
            #pragma unroll
            for (int mt = 0; mt < 4; ++mt)
                #pragma unroll
                for (int j = 0; j < 4; ++j)
                    st[u][mt][j] = EXP_P(st[u][mt][j]);
            #pragma unroll
            for (int t = 0; t < 2; ++t) {
                unsigned w0 = pkrtz(st[u][t][0],     st[u][t][1]);
                unsigned w1 = pkrtz(st[u][t][2],     st[u][t][3]);
                unsigned w2 = pkrtz(st[u][t + 2][0], st[u][t + 2][1]);
                unsigned w3 = pkrtz(st[u][t + 2][2], st[u][t + 2][3]);
                uint4 pw = make_uint4(w0, w1, w2, w3);
                __builtin_memcpy(&pb[u][t], &pw, 16);
            }
            lacc[u] = MFMAH(onesh, pb[u][0], lacc[u], 0, 0, 0);
            lacc[u] = MFMAH(onesh, pb[u][1], lacc[u], 0, 0, 0);
        }

        // ---- O^T += V^T . P^T   (V single fp16, P fp16: 1 MFMA each)
        __builtin_amdgcn_s_setprio(1);
        #pragma unroll
        for (int t = 0; t < 2; ++t) {
            #pragma unroll
            for (int mt = 0; mt < 4; ++mt) {
                const int row = 16 * mt + lq;
                const int swz = (row & 7) << 4;
                const char* vr = L2 + 8192 + row * 128;
                half8 vv = *(const half8*)(vr + ((t * 64 + 16 * lg) ^ swz));
                #pragma unroll
                for (int u = 0; u < 2; ++u)
                    ot[u][mt] = MFMAH(vv, pb[u][t], ot[u][mt], 0, 0, 0);
            }
        }
        __builtin_amdgcn_s_setprio(0);

        __syncthreads();        // drains prefetch vmcnt + protects LDS reuse
        buf ^= 1;
    }

    // ---- epilogue
    if (FUSE) {
        const float gain = 0.25f * (*g0 + *g1 + *g2 + *g3);
        const float ascv = *asc, abiv = *abi;
        const int bb = bh >> 4, hh = bh & 15;
        #pragma unroll
        for (int u = 0; u < 2; ++u) {
            const int m = bb * PS + q0 + 16 * u + lq;
            const unsigned short* mp = modh + (size_t)m * PE + hh * 64 + 4 * lg;
            unsigned short* op = afh + (size_t)m * PE + hh * 64 + 4 * lg;
            const float inv = 1.f / lacc[u][0];
            #pragma unroll
            for (int mt = 0; mt < 4; ++mt) {
                ushort4 mv = *(const ushort4*)(mp + 16 * mt);
                ushort4 ov;
                ov.x = h16((ot[u][mt][0] * inv * ascv + abiv) * (1.f + f16tof(mv.x) * gain));
                ov.y = h16((ot[u][mt][1] * inv * ascv + abiv) * (1.f + f16tof(mv.y) * gain));
                ov.z = h16((ot[u][mt][2] * inv * ascv + abiv) * (1.f + f16tof(mv.z) * gain));
                ov.w = h16((ot[u][mt][3] * inv * ascv + abiv) * (1.f + f16tof(mv.w) * gain));
                *(ushort4*)(op + 16 * mt) = ov;
            }
        }
    } else {
        #pragma unroll
        for (int u = 0; u < 2; ++u) {
            const float inv = 1.f / lacc[u][0];
            float* op = attn + ((size_t)bh * PS + q0 + 16 * u + lq) * PD + 4 * lg;
            #pragma unroll
            for (int mt = 0; mt < 4; ++mt) {
                float4 o;
                o.x = ot[u][mt][0] * inv; o.y = ot[u][mt][1] * inv;
                o.z = ot[u][mt][2] * inv; o.w = ot[u][mt][3] * inv;
                *(float4*)(op + 16 * mt) = o;
            }
        }
    }
}

// ---------------------------------------------------------------------------
extern "C" void kernel_launch(void* const* d_in, const int* in_sizes, int n_in,
                              void* d_out, int out_size, void* d_ws, size_t ws_size,
                              hipStream_t stream)
{
    const float* query = (const float*)d_in[0];
    const float* Wq  = (const float*)d_in[1];  const float* bq  = (const float*)d_in[2];
    const float* Wk  = (const float*)d_in[3];  const float* bk  = (const float*)d_in[4];
    const float* Wv  = (const float*)d_in[5];  const float* bv  = (const float*)d_in[6];
    const float* Wo  = (const float*)d_in[7];  const float* bo  = (const float*)d_in[8];
    const float* Wm1 = (const float*)d_in[9];  const float* bm1 = (const float*)d_in[10];
    const float* Wm2 = (const float*)d_in[11]; const float* bm2 = (const float*)d_in[12];
    const float* dop = (const float*)d_in[13];
    const float* ser = (const float*)d_in[14];
    const float* nor = (const float*)d_in[15];
    const float* ach = (const float*)d_in[16];
    const float* asc = (const float*)d_in[17];
    const float* abi = (const float*)d_in[18];
    float* out = (float*)d_out;

    char* wsb = (char*)d_ws;
    // Common: attn fp32 [0,32M) (fallback), kf [32M,48M), vtf [48M,64M)
    float*          attnb = (float*)wsb;
    unsigned short* kf    = (unsigned short*)(wsb + (32u << 20));
    unsigned short* vtf   = (unsigned short*)(wsb + (48u << 20));

    dim3 blk(256);
    const bool presplit = (ws_size >= 161480704ull);             // 154 MB

    if (presplit) {
        unsigned short* h1h   = (unsigned short*)(wsb + (64u << 20));  // 4MB
        unsigned short* afh   = (unsigned short*)(wsb + (72u << 20));  // 16MB
        unsigned short* qh16  = (unsigned short*)(wsb + (88u << 20));  // 16MB
        unsigned short* modh  = (unsigned short*)(wsb + (120u << 20)); // 16MB
        unsigned short* wqh   = (unsigned short*)(wsb + (136u << 20)); // 2MB
        unsigned short* wkh   = (unsigned short*)(wsb + (138u << 20));
        unsigned short* wvh   = (unsigned short*)(wsb + (140u << 20));
        unsigned short* woh   = (unsigned short*)(wsb + (142u << 20));
        unsigned short* m1h   = (unsigned short*)(wsb + (144u << 20)); // 0.5MB
        unsigned short* m2h   = (unsigned short*)(wsb + (145u << 20));

        split_w<<<4608, blk, 0, stream>>>(
            Wq, Wk, Wv, Wo, Wm1, Wm2,
            wqh, wkh, wvh, woh, m1h, m2h);

        // Fused Q/K/V projections; A = fp32 query converted in-flight
        gemm_qkv<<<dim3(PM / 128, PE / 128), dim3(512), 0, stream>>>(
            query, wqh, wkh, wvh, bq, bk, bv, qh16, kf, vtf);

        // MLP: h1 (fp32 query in-flight) then mod plane
        gemm_m1<<<dim3(PM / 128, 256 / 128), blk, 0, stream>>>(
            query, m1h, bm1, h1h);
        gemm_pl<5, false><<<dim3(PM / 128, PE / 128), blk, 0, stream>>>(
            h1h, m2h, bm2, nullptr, modh, PM, PE, 256);

        // Flash with fused neuromod combine -> fp16 attnf plane
        flash_mfma<1><<<dim3(PS / 128, PH, PB), blk, 0, stream>>>(
            qh16, kf, vtf, modh, dop, ser, nor, ach, asc, abi,
            afh, nullptr);

        // Output projection
        gemm_pl<0, false><<<dim3(PM / 128, PE / 128), blk, 0, stream>>>(
            afh, woh, bo, out, nullptr, PM, PE, PE);
    } else {
        // fallback: fp32-fed bf16 3-term GEMMs + fp16 flash (round-17 flow)
        float* h1    = (float*)(wsb + (64u << 20));   // 8MB
        float* attnf = (float*)(wsb + (72u << 20));   // 32MB
        unsigned short* qh16 = (unsigned short*)(wsb + (72u << 20)); // 16MB

        gemm_nt<1, false><<<dim3(PM / 128, PE / 128), blk, 0, stream>>>(
            query, Wq, bq, nullptr, qh16, PM, PE, PE,
            nullptr, nullptr, nullptr, nullptr, nullptr, nullptr, nullptr);
        gemm_nt<3, false><<<dim3(PM / 128, PE / 128), blk, 0, stream>>>(
            query, Wk, bk, nullptr, kf, PM, PE, PE,
            nullptr, nullptr, nullptr, nullptr, nullptr, nullptr, nullptr);
        gemm_nt<4, false><<<dim3(PM / 128, PE / 128), blk, 0, stream>>>(
            query, Wv, bv, nullptr, vtf, PM, PE, PE,
            nullptr, nullptr, nullptr, nullptr, nullptr, nullptr, nullptr);
        gemm_nt<0, true><<<dim3(PM / 128, 256 / 128), blk, 0, stream>>>(
            query, Wm1, bm1, h1, nullptr, PM, 256, PE,
            nullptr, nullptr, nullptr, nullptr, nullptr, nullptr, nullptr);

        flash_mfma<0><<<dim3(PS / 128, PH, PB), blk, 0, stream>>>(
            qh16, kf, vtf, nullptr, nullptr, nullptr, nullptr, nullptr,
            nullptr, nullptr, nullptr, attnb);

        gemm_nt<2, false><<<dim3(PM / 128, PE / 128), blk, 0, stream>>>(
            h1, Wm2, bm2, attnf, nullptr, PM, PE, 256,
            attnb, dop, ser, nor, ach, asc, abi);
        gemm_nt<0, false><<<dim3(PM / 128, PE / 128), blk, 0, stream>>>(
            attnf, Wo, bo, out, nullptr, PM, PE, PE,
            nullptr, nullptr, nullptr, nullptr, nullptr, nullptr, nullptr);
    }
}

// Round 21
// 200.781 us; speedup vs baseline: 1.6155x; 1.6155x over previous
//
#include <hip/hip_runtime.h>
#include <hip/hip_bf16.h>
#include <cstdint>

// Problem constants
#define PB 4
#define PS 2048
#define PE 1024
#define PH 16
#define PD 64
#define PM (PB * PS)      // 8192 rows

typedef __attribute__((ext_vector_type(8))) _Float16 half8;  // 8 fp16 (4 VGPR)
typedef __attribute__((ext_vector_type(4))) float f32x4;

#define MFMAH __builtin_amdgcn_mfma_f32_16x16x32_f16

#define GLOAD_LDS(gp, lp) __builtin_amdgcn_global_load_lds(                    \
    (const __attribute__((address_space(1))) void*)(gp),                       \
    (__attribute__((address_space(3))) void*)(lp), 16, 0, 0)

#if __has_builtin(__builtin_amdgcn_exp2f)
#define FAST_EXP2 1
#define QSC (0.125f * 1.4426950408889634f)   // exp2 domain
#define FTHR 11.5415603f                     // 8*log2(e)
#define EXP_P(x) __builtin_amdgcn_exp2f(x)
#else
#define FAST_EXP2 0
#define QSC 0.125f
#define FTHR 8.f
#define EXP_P(x) __expf(x)
#endif

// fp32 -> fp16 RNE bit pattern
__device__ inline unsigned short h16(float x) {
    _Float16 h = (_Float16)x;
    unsigned short u;
    __builtin_memcpy(&u, &h, 2);
    return u;
}
__device__ inline float f16tof(unsigned short u) {
    _Float16 h;
    __builtin_memcpy(&h, &u, 2);
    return (float)h;
}
// packed fp16 pair via v_cvt_pkrtz_f16_f32; returns the 32-bit word
__device__ inline unsigned pkrtz(float a, float b) {
    auto p = __builtin_amdgcn_cvt_pkrtz(a, b);   // __fp16 ext_vector(2)
    unsigned u;
    __builtin_memcpy(&u, &p, 4);
    return u;
}

// ---------------------------------------------------------------------------
// split_all: all 7 fp32 operands -> single fp16 planes, one launch.
// ---------------------------------------------------------------------------
__global__ __launch_bounds__(256)
void split_all(const float* __restrict__ q,   const float* __restrict__ wq,
               const float* __restrict__ wk,  const float* __restrict__ wv,
               const float* __restrict__ wo,  const float* __restrict__ wm1,
               const float* __restrict__ wm2,
               unsigned short* qh,  unsigned short* wqh, unsigned short* wkh,
               unsigned short* wvh, unsigned short* woh,
               unsigned short* m1h, unsigned short* m2h)
{
    const int b = blockIdx.x;
    const float* src; unsigned short* dst; int base;
    if      (b <  8192) { src = q;   dst = qh;  base = 0;     }
    else if (b <  9216) { src = wq;  dst = wqh; base = 8192;  }
    else if (b < 10240) { src = wk;  dst = wkh; base = 9216;  }
    else if (b < 11264) { src = wv;  dst = wvh; base = 10240; }
    else if (b < 12288) { src = wo;  dst = woh; base = 11264; }
    else if (b < 12544) { src = wm1; dst = m1h; base = 12288; }
    else                { src = wm2; dst = m2h; base = 12544; }
    const int i = (b - base) * 256 + threadIdx.x;
    float4 f = ((const float4*)src)[i];
    ushort4 h;
    h.x = h16(f.x); h.y = h16(f.y); h.z = h16(f.z); h.w = h16(f.w);
    ((ushort4*)dst)[i] = h;
}

// ---------------------------------------------------------------------------
// Fused QKV projection (round-16/19 proven): 512 threads, 128KB dbuf LDS,
// stages A once for Q/K/V via global_load_lds. Epilogues: Q fp16 PRE-SCALED
// at BHSD, K fp16 BHSD, V fp16 BHDS with PV seq permutation.
// ---------------------------------------------------------------------------
__global__ __launch_bounds__(512, 2)
void gemm_qkv(const unsigned short* __restrict__ Ah,
              const unsigned short* __restrict__ Wqh,
              const unsigned short* __restrict__ Wkh,
              const unsigned short* __restrict__ Wvh,
              const float* __restrict__ bq, const float* __restrict__ bk,
              const float* __restrict__ bv,
              unsigned short* __restrict__ qh16, unsigned short* __restrict__ kf,
              unsigned short* __restrict__ vtf)
{
    __shared__ int4 ldsq[8192];                 // 128 KB = 2 bufs x 4 planes
    char* const lds = (char*)ldsq;
    const int K = PE;

    const int tid  = threadIdx.x;
    const int lane = tid & 63;
    const int w    = tid >> 6;
    const int lq   = lane & 15;
    const int lg   = lane >> 4;
    const int wr   = w >> 2;
    const int wc   = w & 3;
    const int m0   = blockIdx.x * 128;
    const int n0   = blockIdx.y * 128;

    const int plane = w >> 1;
    const unsigned short* const gp =
        (plane == 0) ? Ah  + (size_t)m0 * K :
        (plane == 1) ? Wqh + (size_t)n0 * K :
        (plane == 2) ? Wkh + (size_t)n0 * K :
                       Wvh + (size_t)n0 * K;
    const int pbase = plane * 16384;
    const int ch0   = (w & 1) * 8;
    const int scol8 = (((lane & 7) ^ (lane >> 3)) << 3);
    const int lrow8 = lane >> 3;

    auto ISSUE = [&](int k0, int bufn) {
        #pragma unroll
        for (int r = 0; r < 8; ++r) {
            const int c   = ch0 + r;
            const int row = c * 8 + lrow8;
            GLOAD_LDS(gp + (size_t)row * K + k0 + scol8,
                      lds + bufn * 65536 + pbase + c * 1024 + 16 * lane);
        }
    };

    f32x4 acc[3][4][2];
    #pragma unroll
    for (int o = 0; o < 3; ++o)
        #pragma unroll
        for (int mt = 0; mt < 4; ++mt)
            #pragma unroll
            for (int nt = 0; nt < 2; ++nt)
                acc[o][mt][nt] = (f32x4){0.f, 0.f, 0.f, 0.f};

    ISSUE(0, 0);
    __syncthreads();

    int buf = 0;
    for (int k0 = 0; k0 < K; k0 += 64) {
        if (k0 + 64 < K) ISSUE(k0 + 64, buf ^ 1);

        const char* const L = lds + buf * 65536;
        #pragma unroll
        for (int kh = 0; kh < 2; ++kh) {
            half8 af[4];
            #pragma unroll
            for (int mt = 0; mt < 4; ++mt) {
                const int row = 64 * wr + 16 * mt + lq;
                const int off = row * 128 + ((kh * 64 + 16 * lg) ^ ((row & 7) << 4));
                af[mt] = *(const half8*)(L + off);
            }
            #pragma unroll
            for (int o = 0; o < 3; ++o) {
                #pragma unroll
                for (int nt = 0; nt < 2; ++nt) {
                    const int row = 32 * wc + 16 * nt + lq;
                    const int off = row * 128 + ((kh * 64 + 16 * lg) ^ ((row & 7) << 4));
                    half8 bf = *(const half8*)(L + 16384 * (o + 1) + off);
                    #pragma unroll
                    for (int mt = 0; mt < 4; ++mt)
                        acc[o][mt][nt] = MFMAH(af[mt], bf, acc[o][mt][nt], 0, 0, 0);
                }
            }
        }
        __syncthreads();
        buf ^= 1;
    }

    #pragma unroll
    for (int nt = 0; nt < 2; ++nt) {
        const int n = n0 + 32 * wc + 16 * nt + lq;
        const int h = n >> 6, d = n & 63;
        const float bqv = bq[n], bkv = bk[n], bvv = bv[n];
        #pragma unroll
        for (int mt = 0; mt < 4; ++mt) {
            #pragma unroll
            for (int j = 0; j < 4; ++j) {
                const int m = m0 + 64 * wr + 16 * mt + 4 * lg + j;
                const int b = m >> 11, s = m & 2047;
                qh16[((size_t)(b * PH + h) * PS + s) * PD + d] =
                    h16((acc[0][mt][nt][j] + bqv) * QSC);
                kf[((size_t)(b * PH + h) * PS + s) * PD + d] =
                    h16(acc[1][mt][nt][j] + bkv);
                const int scol = (s & ~63) + ((mt & 1) << 5) + (lg << 3)
                               + ((mt >> 1) << 2) + j;
                vtf[((size_t)(b * PH + h) * PD + d) * PS + scol] =
                    h16(acc[2][mt][nt][j] + bvv);
            }
        }
    }
}

// ---------------------------------------------------------------------------
// Plane-fed single-fp16 MFMA NT GEMM (round-15 proven engine, unchanged).
// MODE 0: fp32 C[m*N+n] (optional RELU) | MODE 5: fp16 plane [M][N]
// ---------------------------------------------------------------------------
template<int MODE, bool RELU>
__global__ __launch_bounds__(256, 2)
void gemm_pl(const unsigned short* __restrict__ Ah,
             const unsigned short* __restrict__ Bh,
             const float* __restrict__ bias, float* __restrict__ C,
             unsigned short* __restrict__ Oh,
             int M, int N, int K)
{
    __shared__ int4 ldsq[4096];                 // 64 KB = 2 bufs x 32 KB
    char* const lds = (char*)ldsq;

    const int tid  = threadIdx.x;
    const int lane = tid & 63;
    const int w    = tid >> 6;
    const int lq   = lane & 15;
    const int lg   = lane >> 4;
    const int wm   = (w >> 1) * 64;
    const int wn   = (w & 1) * 64;
    const int m0   = blockIdx.x * 128;
    const int n0   = blockIdx.y * 128;

    const unsigned short* const gp =
        (w < 2) ? Ah + (size_t)m0 * K : Bh + (size_t)n0 * K;
    const int pb    = (w < 2) ? 0 : 16384;
    const int ch0   = (w & 1) * 8;
    const int scol8 = (((lane & 7) ^ (lane >> 3)) << 3);
    const int lrow8 = lane >> 3;

    auto ISSUE = [&](int k0, int bufn) {
        #pragma unroll
        for (int r = 0; r < 8; ++r) {
            const int c   = ch0 + r;
            const int row = c * 8 + lrow8;
            GLOAD_LDS(gp + (size_t)row * K + k0 + scol8,
                      lds + bufn * 32768 + pb + c * 1024 + 16 * lane);
        }
    };

    f32x4 acc[4][4];
    #pragma unroll
    for (int mt = 0; mt < 4; ++mt)
        #pragma unroll
        for (int nt = 0; nt < 4; ++nt)
            acc[mt][nt] = (f32x4){0.f, 0.f, 0.f, 0.f};

    ISSUE(0, 0);
    __syncthreads();

    int buf = 0;
    for (int k0 = 0; k0 < K; k0 += 64) {
        if (k0 + 64 < K) ISSUE(k0 + 64, buf ^ 1);

        const char* const L = lds + buf * 32768;
        #pragma unroll
        for (int kh = 0; kh < 2; ++kh) {
            half8 af[4];
            #pragma unroll
            for (int mt = 0; mt < 4; ++mt) {
                const int row = wm + 16 * mt + lq;
                const int off = row * 128 + ((kh * 64 + 16 * lg) ^ ((row & 7) << 4));
                af[mt] = *(const half8*)(L + off);
            }
            #pragma unroll
            for (int nt = 0; nt < 4; ++nt) {
                const int row = wn + 16 * nt + lq;
                const int off = row * 128 + ((kh * 64 + 16 * lg) ^ ((row & 7) << 4));
                half8 bf = *(const half8*)(L + 16384 + off);
                #pragma unroll
                for (int mt = 0; mt < 4; ++mt)
                    acc[mt][nt] = MFMAH(af[mt], bf, acc[mt][nt], 0, 0, 0);
            }
        }
        __syncthreads();
        buf ^= 1;
    }

    #pragma unroll
    for (int nt = 0; nt < 4; ++nt) {
        const int n  = n0 + wn + 16 * nt + lq;
        const float bv = bias[n];
        #pragma unroll
        for (int mt = 0; mt < 4; ++mt) {
            #pragma unroll
            for (int j = 0; j < 4; ++j) {
                const int m = m0 + wm + 16 * mt + 4 * lg + j;
                float v = acc[mt][nt][j] + bv;
                if (RELU) v = fmaxf(v, 0.f);
                if (MODE == 0) {
                    C[(size_t)m * N + n] = v;
                } else { // MODE 5
                    Oh[(size_t)m * N + n] = h16(v);
                }
            }
        }
    }
}

// ---------------------------------------------------------------------------
// fp32-fed fallback GEMM (bf16 3-term internally, round-5 proven skeleton);
// MODE 1 emits PRE-SCALED fp16 Q; MODE 3/4 emit fp16 planes.
// ---------------------------------------------------------------------------
typedef __attribute__((ext_vector_type(8))) short short8;
#define MFMA16 __builtin_amdgcn_mfma_f32_16x16x32_bf16
__device__ inline unsigned short bf16rn(float x) {
    unsigned u = __builtin_bit_cast(unsigned, x);
    u += 0x7FFFu + ((u >> 16) & 1u);
    return (unsigned short)(u >> 16);
}
__device__ inline float bf16tof(unsigned short h) {
    unsigned u = ((unsigned)h) << 16;
    return __builtin_bit_cast(float, u);
}
__device__ inline void split2(float x, unsigned short& h, unsigned short& l) {
    h = bf16rn(x);
    l = bf16rn(x - bf16tof(h));
}

template<int MODE, bool RELU>
__global__ __launch_bounds__(256, 2)
void gemm_nt(const float* __restrict__ A, const float* __restrict__ Bw,
             const float* __restrict__ bias, float* __restrict__ C,
             unsigned short* __restrict__ Ohi,
             int M, int N, int K,
             const float* __restrict__ attn,
             const float* __restrict__ g0, const float* __restrict__ g1,
             const float* __restrict__ g2, const float* __restrict__ g3,
             const float* __restrict__ asc, const float* __restrict__ abi)
{
    __shared__ int4 ldsq[4096];
    char* const lds = (char*)ldsq;

    const int tid  = threadIdx.x;
    const int lane = tid & 63;
    const int w    = tid >> 6;
    const int lq   = lane & 15;
    const int lg   = lane >> 4;
    const int wm   = (w >> 1) * 64;
    const int wn   = (w & 1) * 64;
    const int m0   = blockIdx.x * 128;
    const int n0   = blockIdx.y * 128;

    const int irow = tid >> 3;
    const int ic8  = (tid & 7) * 8;
    const int woff = (ic8 * 2);

    f32x4 acc[4][4];
    #pragma unroll
    for (int mt = 0; mt < 4; ++mt)
        #pragma unroll
        for (int nt = 0; nt < 4; ++nt)
            acc[mt][nt] = (f32x4){0.f, 0.f, 0.f, 0.f};

    for (int k0 = 0; k0 < K; k0 += 64) {
        #pragma unroll
        for (int mat = 0; mat < 2; ++mat) {
            const float* const src = mat ? Bw : A;
            const int rbase = mat ? n0 : m0;
            const int pbase = mat ? 32768 : 0;
            #pragma unroll
            for (int r = 0; r < 4; ++r) {
                const int row = irow + 32 * r;
                const float* p = src + (size_t)(rbase + row) * K + k0 + ic8;
                float4 f0 = *(const float4*)p;
                float4 f1 = *(const float4*)(p + 4);
                short8 vh, vl;
                {
                    unsigned short h, l;
                    split2(f0.x, h, l); vh[0] = (short)h; vl[0] = (short)l;
                    split2(f0.y, h, l); vh[1] = (short)h; vl[1] = (short)l;
                    split2(f0.z, h, l); vh[2] = (short)h; vl[2] = (short)l;
                    split2(f0.w, h, l); vh[3] = (short)h; vl[3] = (short)l;
                    split2(f1.x, h, l); vh[4] = (short)h; vl[4] = (short)l;
                    split2(f1.y, h, l); vh[5] = (short)h; vl[5] = (short)l;
                    split2(f1.z, h, l); vh[6] = (short)h; vl[6] = (short)l;
                    split2(f1.w, h, l); vh[7] = (short)h; vl[7] = (short)l;
                }
                const int off = row * 128 + (woff ^ ((row & 7) << 4));
                *(short8*)(lds + pbase + off)         = vh;
                *(short8*)(lds + pbase + 16384 + off) = vl;
            }
        }
        __syncthreads();

        #pragma unroll
        for (int kh = 0; kh < 2; ++kh) {
            short8 afh[4], afl[4];
            #pragma unroll
            for (int mt = 0; mt < 4; ++mt) {
                const int row = wm + 16 * mt + lq;
                const int off = row * 128 + ((kh * 64 + 16 * lg) ^ ((row & 7) << 4));
                afh[mt] = *(const short8*)(lds + off);
                afl[mt] = *(const short8*)(lds + 16384 + off);
            }
            #pragma unroll
            for (int nt = 0; nt < 4; ++nt) {
                const int row = wn + 16 * nt + lq;
                const int off = row * 128 + ((kh * 64 + 16 * lg) ^ ((row & 7) << 4));
                short8 bfh = *(const short8*)(lds + 32768 + off);
                short8 bfl = *(const short8*)(lds + 49152 + off);
                #pragma unroll
                for (int mt = 0; mt < 4; ++mt) {
                    acc[mt][nt] = MFMA16(afh[mt], bfh, acc[mt][nt], 0, 0, 0);
                    acc[mt][nt] = MFMA16(afh[mt], bfl, acc[mt][nt], 0, 0, 0);
                    acc[mt][nt] = MFMA16(afl[mt], bfh, acc[mt][nt], 0, 0, 0);
                }
            }
        }
        __syncthreads();
    }

    float gain = 0.f, ascv = 0.f, abiv = 0.f;
    if (MODE == 2) {
        gain = 0.25f * (*g0 + *g1 + *g2 + *g3);
        ascv = *asc;
        abiv = *abi;
    }

    #pragma unroll
    for (int nt = 0; nt < 4; ++nt) {
        const int n  = n0 + wn + 16 * nt + lq;
        const float bv = bias[n];
        #pragma unroll
        for (int mt = 0; mt < 4; ++mt) {
            #pragma unroll
            for (int j = 0; j < 4; ++j) {
                const int m = m0 + wm + 16 * mt + 4 * lg + j;
                float v = acc[mt][nt][j] + bv;
                if (RELU) v = fmaxf(v, 0.f);
                if (MODE == 0) {
                    C[(size_t)m * N + n] = v;
                } else if (MODE == 1) {
                    const int b = m >> 11, s = m & 2047;
                    const int h = n >> 6, d = n & 63;
                    Ohi[((size_t)(b * PH + h) * PS + s) * PD + d] = h16(v * QSC);
                } else if (MODE == 3) {
                    const int b = m >> 11, s = m & 2047;
                    const int h = n >> 6, d = n & 63;
                    Ohi[((size_t)(b * PH + h) * PS + s) * PD + d] = h16(v);
                } else if (MODE == 4) {
                    const int b = m >> 11;
                    const int h = n >> 6, d = n & 63;
                    const int scol = (m & 2047 & ~63) + ((mt & 1) << 5)
                                   + (lg << 3) + ((mt >> 1) << 2) + j;
                    Ohi[((size_t)(b * PH + h) * PD + d) * PS + scol] = h16(v);
                } else { // MODE 2
                    const int b = m >> 11, s = m & 2047;
                    const int h = n >> 6, d = n & 63;
                    const float av = attn[((size_t)(b * PH + h) * PS + s) * PD + d];
                    C[(size_t)m * N + n] = (av * ascv + abiv) * (1.f + v * gain);
                }
            }
        }
    }
}

// ---------------------------------------------------------------------------
// MFMA flash attention v12 (round-19 proven, unchanged): biased C-init
// (st = S - m from the matrix pipe), local-max defer check, setprio around
// MFMA clusters, Q/K/V single fp16, P fp16, l via MFMA(ones,P).
// FUSE=1: epilogue applies neuromod combine -> fp16 attnf plane.
// FUSE=0: fp32 attn BHSD (fallback path).
// ---------------------------------------------------------------------------
template<int FUSE>
__global__ __launch_bounds__(256, 4)
void flash_mfma(const unsigned short* __restrict__ qh16,
                const unsigned short* __restrict__ kf,
                const unsigned short* __restrict__ vtf,
                const unsigned short* __restrict__ modh,
                const float* __restrict__ g0, const float* __restrict__ g1,
                const float* __restrict__ g2, const float* __restrict__ g3,
                const float* __restrict__ asc, const float* __restrict__ abi,
                unsigned short* __restrict__ afh, float* __restrict__ attn)
{
    __shared__ int4 ldsv[2048];                    // 32 KB: 2 bufs x (K8K + V8K)
    char* const ldsb = (char*)ldsv;

    const int tid  = threadIdx.x;
    const int lane = tid & 63;
    const int w    = tid >> 6;
    const int lq   = lane & 15;
    const int lg   = lane >> 4;

    // XCD swizzle: each XCD owns 128 consecutive logical blocks (= 8 bh).
    const int L  = blockIdx.x + (blockIdx.y << 4) + (blockIdx.z << 8);
    const int nL = ((L & 7) << 7) + (L >> 3);
    const int bh = nL >> 4;
    const int q0 = (nL & 15) * 128 + w * 32;

    const size_t kbase = (size_t)bh * PS * PD;   // K rows   [S][D]
    const size_t vbase = (size_t)bh * PD * PS;   // V^T rows [D][S] (permuted)

    const unsigned short* const gp = (w < 2) ? kf + kbase : vtf + vbase;
    const bool isK = (w < 2);
    const int ch0   = (w & 1) * 4;
    const int scol8 = (((lane & 7) ^ (lane >> 3)) << 3);   // pre-swizzled col
    const int lrow8 = lane >> 3;

    auto ISSUE = [&](int kt, int bufn) {
        #pragma unroll
        for (int r = 0; r < 4; ++r) {
            const int c   = ch0 + r;
            const int row = c * 8 + lrow8;
            const size_t goff = isK ? (size_t)(kt + row) * PD + scol8
                                    : (size_t)row * PS + kt + scol8;
            GLOAD_LDS(gp + goff,
                      ldsb + bufn * 16384 + (isK ? 0 : 8192) + c * 1024 + 16 * lane);
        }
    };

    const half8 onesh = {(_Float16)1.f, (_Float16)1.f, (_Float16)1.f,
                         (_Float16)1.f, (_Float16)1.f, (_Float16)1.f,
                         (_Float16)1.f, (_Float16)1.f};

    // ---- Q fragments: pre-scaled fp16 plane, direct vector loads
    half8 qh[2][2];
    #pragma unroll
    for (int u = 0; u < 2; ++u) {
        const unsigned short* qp =
            qh16 + ((size_t)bh * PS + q0 + 16 * u + lq) * PD + 8 * lg;
        qh[u][0] = *(const half8*)(qp);
        qh[u][1] = *(const half8*)(qp + 32);
    }

    f32x4 ot[2][4];
    #pragma unroll
    for (int u = 0; u < 2; ++u)
        #pragma unroll
        for (int mt = 0; mt < 4; ++mt)
            ot[u][mt] = (f32x4){0.f, 0.f, 0.f, 0.f};
    f32x4 lacc[2] = {{0.f,0.f,0.f,0.f}, {0.f,0.f,0.f,0.f}};
    float m_run[2] = {0.f, 0.f};           // absolute running max (biased init)

    ISSUE(0, 0);
    __syncthreads();

    int buf = 0;
    for (int kti = 0; kti < PS / 64; ++kti) {
        const bool pf = (kti + 1 < PS / 64);
        if (pf) ISSUE((kti + 1) * 64, buf ^ 1);

        const char* const L2 = ldsb + buf * 16384;

        // ---- S^T tiles with biased C-init: st = S - m_run (no subs later)
        f32x4 st[2][4];
        __builtin_amdgcn_s_setprio(1);
        #pragma unroll
        for (int mt = 0; mt < 4; ++mt) {
            const int row = 16 * mt + lq;
            const int swz = (row & 7) << 4;
            const char* kr = L2 + row * 128;
            half8 a0 = *(const half8*)(kr + ((16 * lg) ^ swz));
            half8 a1 = *(const half8*)(kr + ((64 + 16 * lg) ^ swz));
            #pragma unroll
            for (int u = 0; u < 2; ++u) {
                const float nm = -m_run[u];
                f32x4 acc = {nm, nm, nm, nm};
                acc = MFMAH(a0, qh[u][0], acc, 0, 0, 0);
                acc = MFMAH(a1, qh[u][1], acc, 0, 0, 0);
                st[u][mt] = acc;
            }
        }
        __builtin_amdgcn_s_setprio(0);

        // ---- online softmax (defer-max, biased) + P pack + l via MFMA
        half8 pb[2][2];
        #pragma unroll
        for (int u = 0; u < 2; ++u) {
            float a0 = fmaxf(fmaxf(st[u][0][0], st[u][0][1]), st[u][0][2]);
            float a1 = fmaxf(fmaxf(st[u][0][3], st[u][1][0]), st[u][1][1]);
            float a2 = fmaxf(fmaxf(st[u][1][2], st[u][1][3]), st[u][2][0]);
            float a3 = fmaxf(fmaxf(st[u][2][1], st[u][2][2]), st[u][2][3]);
            float a4 = fmaxf(fmaxf(st[u][3][0], st[u][3][1]), st[u][3][2]);
            float b0 = fmaxf(fmaxf(a0, a1), a2);
            float b1 = fmaxf(fmaxf(a3, a4), st[u][3][3]);
            float lmax = fmaxf(b0, b1);
            if (!__all(lmax <= FTHR)) {            // rare: rescale path
                float pmax = fmaxf(lmax, __shfl_xor(lmax, 16));
                pmax = fmaxf(pmax, __shfl_xor(pmax, 32));
                float corr = EXP_P(-pmax);
                m_run[u] += pmax;
                #pragma unroll
                for (int j = 0; j < 4; ++j)
                    lacc[u][j] *= corr;
                #pragma unroll
                for (int mt = 0; mt < 4; ++mt)
                    #pragma unroll
                    for (int j = 0; j < 4; ++j) {
                        ot[u][mt][j] *= corr;
                        st[u][mt][j] -= pmax;
                    }
            }
            #pragma unroll
            for (int mt = 0; mt < 4; ++mt)
                #pragma unroll
                for (int j = 0; j < 4; ++j)
                    st[u][mt][j] = EXP_P(st[u][mt][j]);
            #pragma unroll
            for (int t = 0; t < 2; ++t) {
                unsigned w0 = pkrtz(st[u][t][0],     st[u][t][1]);
                unsigned w1 = pkrtz(st[u][t][2],     st[u][t][3]);
                unsigned w2 = pkrtz(st[u][t + 2][0], st[u][t + 2][1]);
                unsigned w3 = pkrtz(st[u][t + 2][2], st[u][t + 2][3]);
                uint4 pw = make_uint4(w0, w1, w2, w3);
                __builtin_memcpy(&pb[u][t], &pw, 16);
            }
            lacc[u] = MFMAH(onesh, pb[u][0], lacc[u], 0, 0, 0);
            lacc[u] = MFMAH(onesh, pb[u][1], lacc[u], 0, 0, 0);
        }

        // ---- O^T += V^T . P^T   (V single fp16, P fp16: 1 MFMA each)
        __builtin_amdgcn_s_setprio(1);
        #pragma unroll
        for (int t = 0; t < 2; ++t) {
            #pragma unroll
            for (int mt = 0; mt < 4; ++mt) {
                const int row = 16 * mt + lq;
                const int swz = (row & 7) << 4;
                const char* vr = L2 + 8192 + row * 128;
                half8 vv = *(const half8*)(vr + ((t * 64 + 16 * lg) ^ swz));
                #pragma unroll
                for (int u = 0; u < 2; ++u)
                    ot[u][mt] = MFMAH(vv, pb[u][t], ot[u][mt], 0, 0, 0);
            }
        }
        __builtin_amdgcn_s_setprio(0);

        __syncthreads();        // drains prefetch vmcnt + protects LDS reuse
        buf ^= 1;
    }

    // ---- epilogue
    if (FUSE) {
        const float gain = 0.25f * (*g0 + *g1 + *g2 + *g3);
        const float ascv = *asc, abiv = *abi;
        const int bb = bh >> 4, hh = bh & 15;
        #pragma unroll
        for (int u = 0; u < 2; ++u) {
            const int m = bb * PS + q0 + 16 * u + lq;
            const unsigned short* mp = modh + (size_t)m * PE + hh * 64 + 4 * lg;
            unsigned short* op = afh + (size_t)m * PE + hh * 64 + 4 * lg;
            const float inv = 1.f / lacc[u][0];
            #pragma unroll
            for (int mt = 0; mt < 4; ++mt) {
                ushort4 mv = *(const ushort4*)(mp + 16 * mt);
                ushort4 ov;
                ov.x = h16((ot[u][mt][0] * inv * ascv + abiv) * (1.f + f16tof(mv.x) * gain));
                ov.y = h16((ot[u][mt][1] * inv * ascv + abiv) * (1.f + f16tof(mv.y) * gain));
                ov.z = h16((ot[u][mt][2] * inv * ascv + abiv) * (1.f + f16tof(mv.z) * gain));
                ov.w = h16((ot[u][mt][3] * inv * ascv + abiv) * (1.f + f16tof(mv.w) * gain));
                *(ushort4*)(op + 16 * mt) = ov;
            }
        }
    } else {
        #pragma unroll
        for (int u = 0; u < 2; ++u) {
            const float inv = 1.f / lacc[u][0];
            float* op = attn + ((size_t)bh * PS + q0 + 16 * u + lq) * PD + 4 * lg;
            #pragma unroll
            for (int mt = 0; mt < 4; ++mt) {
                float4 o;
                o.x = ot[u][mt][0] * inv; o.y = ot[u][mt][1] * inv;
                o.z = ot[u][mt][2] * inv; o.w = ot[u][mt][3] * inv;
                *(float4*)(op + 16 * mt) = o;
            }
        }
    }
}

// ---------------------------------------------------------------------------
extern "C" void kernel_launch(void* const* d_in, const int* in_sizes, int n_in,
                              void* d_out, int out_size, void* d_ws, size_t ws_size,
                              hipStream_t stream)
{
    const float* query = (const float*)d_in[0];
    const float* Wq  = (const float*)d_in[1];  const float* bq  = (const float*)d_in[2];
    const float* Wk  = (const float*)d_in[3];  const float* bk  = (const float*)d_in[4];
    const float* Wv  = (const float*)d_in[5];  const float* bv  = (const float*)d_in[6];
    const float* Wo  = (const float*)d_in[7];  const float* bo  = (const float*)d_in[8];
    const float* Wm1 = (const float*)d_in[9];  const float* bm1 = (const float*)d_in[10];
    const float* Wm2 = (const float*)d_in[11]; const float* bm2 = (const float*)d_in[12];
    const float* dop = (const float*)d_in[13];
    const float* ser = (const float*)d_in[14];
    const float* nor = (const float*)d_in[15];
    const float* ach = (const float*)d_in[16];
    const float* asc = (const float*)d_in[17];
    const float* abi = (const float*)d_in[18];
    float* out = (float*)d_out;

    char* wsb = (char*)d_ws;
    // Common: attn fp32 [0,32M) (fallback), kf [32M,48M), vtf [48M,64M)
    float*          attnb = (float*)wsb;
    unsigned short* kf    = (unsigned short*)(wsb + (32u << 20));
    unsigned short* vtf   = (unsigned short*)(wsb + (48u << 20));

    dim3 blk(256);
    const bool presplit = (ws_size >= 161480704ull);             // 154 MB

    if (presplit) {
        unsigned short* h1h   = (unsigned short*)(wsb + (64u << 20));  // 4MB
        unsigned short* afh   = (unsigned short*)(wsb + (72u << 20));  // 16MB
        unsigned short* qh16  = (unsigned short*)(wsb + (88u << 20));  // 16MB
        unsigned short* qh    = (unsigned short*)(wsb + (104u << 20)); // 16MB
        unsigned short* modh  = (unsigned short*)(wsb + (120u << 20)); // 16MB
        unsigned short* wqh   = (unsigned short*)(wsb + (136u << 20)); // 2MB
        unsigned short* wkh   = (unsigned short*)(wsb + (138u << 20));
        unsigned short* wvh   = (unsigned short*)(wsb + (140u << 20));
        unsigned short* woh   = (unsigned short*)(wsb + (142u << 20));
        unsigned short* m1h   = (unsigned short*)(wsb + (144u << 20)); // 0.5MB
        unsigned short* m2h   = (unsigned short*)(wsb + (145u << 20));

        split_all<<<12800, blk, 0, stream>>>(
            query, Wq, Wk, Wv, Wo, Wm1, Wm2,
            qh, wqh, wkh, wvh, woh, m1h, m2h);

        // Fused Q/K/V projections; Q emitted fp16 pre-scaled
        gemm_qkv<<<dim3(PM / 128, PE / 128), dim3(512), 0, stream>>>(
            qh, wqh, wkh, wvh, bq, bk, bv, qh16, kf, vtf);

        // MLP (independent of attention): h1 then mod plane
        gemm_pl<5, true><<<dim3(PM / 128, 256 / 128), blk, 0, stream>>>(
            qh, m1h, bm1, nullptr, h1h, PM, 256, PE);
        gemm_pl<5, false><<<dim3(PM / 128, PE / 128), blk, 0, stream>>>(
            h1h, m2h, bm2, nullptr, modh, PM, PE, 256);

        // Flash with fused neuromod combine -> fp16 attnf plane
        flash_mfma<1><<<dim3(PS / 128, PH, PB), blk, 0, stream>>>(
            qh16, kf, vtf, modh, dop, ser, nor, ach, asc, abi,
            afh, nullptr);

        // Output projection
        gemm_pl<0, false><<<dim3(PM / 128, PE / 128), blk, 0, stream>>>(
            afh, woh, bo, out, nullptr, PM, PE, PE);
    } else {
        // fallback: fp32-fed bf16 3-term GEMMs + fp16 flash (round-17 flow)
        float* h1    = (float*)(wsb + (64u << 20));   // 8MB
        float* attnf = (float*)(wsb + (72u << 20));   // 32MB
        unsigned short* qh16 = (unsigned short*)(wsb + (72u << 20)); // 16MB

        gemm_nt<1, false><<<dim3(PM / 128, PE / 128), blk, 0, stream>>>(
            query, Wq, bq, nullptr, qh16, PM, PE, PE,
            nullptr, nullptr, nullptr, nullptr, nullptr, nullptr, nullptr);
        gemm_nt<3, false><<<dim3(PM / 128, PE / 128), blk, 0, stream>>>(
            query, Wk, bk, nullptr, kf, PM, PE, PE,
            nullptr, nullptr, nullptr, nullptr, nullptr, nullptr, nullptr);
        gemm_nt<4, false><<<dim3(PM / 128, PE / 128), blk, 0, stream>>>(
            query, Wv, bv, nullptr, vtf, PM, PE, PE,
            nullptr, nullptr, nullptr, nullptr, nullptr, nullptr, nullptr);
        gemm_nt<0, true><<<dim3(PM / 128, 256 / 128), blk, 0, stream>>>(
            query, Wm1, bm1, h1, nullptr, PM, 256, PE,
            nullptr, nullptr, nullptr, nullptr, nullptr, nullptr, nullptr);

        flash_mfma<0><<<dim3(PS / 128, PH, PB), blk, 0, stream>>>(
            qh16, kf, vtf, nullptr, nullptr, nullptr, nullptr, nullptr,
            nullptr, nullptr, nullptr, attnb);

        gemm_nt<2, false><<<dim3(PM / 128, PE / 128), blk, 0, stream>>>(
            h1, Wm2, bm2, attnf, nullptr, PM, PE, 256,
            attnb, dop, ser, nor, ach, asc, abi);
        gemm_nt<0, false><<<dim3(PM / 128, PE / 128), blk, 0, stream>>>(
            attnf, Wo, bo, out, nullptr, PM, PE, PE,
            nullptr, nullptr, nullptr, nullptr, nullptr, nullptr, nullptr);
    }
}